// Round 10
// baseline (40.397 us; speedup 1.0000x reference)
//
#include <hip/hip_runtime.h>

typedef unsigned int uint_t;
typedef unsigned short u16;

#define LL 8192
#define TT 32
#define NGPB 2047                    // 4-sample groups per batch
#define NGROUPS 16376                // 8 * NGPB
#define NSAMP 65504                  // samples per track
#define KS16 65536                   // per-track key stride (ushorts)
#define NBINS 1000
#define K1_BLOCKS 256
#define OV_CAP 8
#define HSTRIDE 260                  // LDS row stride (ints)
#define NHIST 128                    // hist blocks (32 tracks x 4 row-quarters)
#define NZB 1920                     // zero blocks in K2 (grid 2048, refills CUs)
#define REGION_A 5952000             // int4s: rows 256..999, all tracks
#define REGION_TOT 7475712           // + rows 0..255 x cols 256..999
#define ZA1 3000000                  // int4s zeroed by K1 (48 MB: balances K1/K2 BW)
// ws layout (ints): [0,256) ov counts; [256,2304) ov records; keys @ int 4096
#define WS_CNT_OFF 0
#define WS_REC_OFF 256
#define WS_KEYS_INT_OFF 4096
#define WS_NEEDED ((size_t)WS_KEYS_INT_OFF * 4 + (size_t)TT * KS16 * 2)

__device__ __forceinline__ int bin_of(float v) {
    v = fminf(fmaxf(v, 0.0f), 10.0f);
    int b = (int)ceilf(v * 100.0f) - 1;
    b = b < 0 ? 0 : b;
    return b > (NBINS - 1) ? (NBINS - 1) : b;
}

__device__ __forceinline__ int4* zaddr(int4* __restrict__ j4, int v) {
    if (v < REGION_A) {                       // rows 256..999, full width
        const int trk = v / 186000;
        const int rem = v - trk * 186000;
        return j4 + (size_t)trk * 250000 + 64000 + rem;
    } else {                                  // rows 0..255, cols 256..999
        const int w   = v - REGION_A;
        const int trk = w / 47616;
        const int rem = w - trk * 47616;
        const int r   = rem / 186;
        const int c4  = rem - r * 186;
        return j4 + (size_t)trk * 250000 + r * 250 + 64 + c4;
    }
}

// ---- K1: zero 48MB share + marginals; bin (float4 track-quads) -> u16 keys ----
__global__ __launch_bounds__(512) void k1_bin(
    const float* __restrict__ yp, const float* __restrict__ yt,
    int* __restrict__ out, int* __restrict__ ws)
{
    __shared__ int s_ovc;
    const int tid = threadIdx.x;
    const int bid = blockIdx.x;
    if (tid == 0) s_ovc = 0;
    if (tid < 250) out[bid * 250 + tid] = 0;          // 256*250 = 64,000 marginal ints
    __syncthreads();

    // zero share first: stores drain under the bin compute below
    int4* __restrict__ j4 = (int4*)(out + 2 * TT * NBINS);
    for (int v = bid * 512 + tid; v < ZA1; v += K1_BLOCKS * 512)
        *zaddr(j4, v) = make_int4(0, 0, 0, 0);

    u16* __restrict__ keys = (u16*)(ws + WS_KEYS_INT_OFF);
    const int trkq  = tid & 7;                        // track quad (4 tracks)
    const int slotg = tid >> 3;                       // 0..63
    const int g = bid * 64 + slotg;

    if (g < NGROUPS) {
        const int b = g / NGPB;
        const int j = g - b * NGPB;
        const float4* __restrict__ yp4 = (const float4*)yp;
        const float4* __restrict__ yt4 = (const float4*)yt;
        const size_t base4 = ((size_t)b * LL + 4 * (size_t)j) * 8 + trkq;  // float4 units
        float4 xp[8], xt[8];
        #pragma unroll
        for (int k = 0; k < 8; ++k) {                 // 8 lanes x 16B = 128B segments
            xp[k] = yp4[base4 + (size_t)k * 8];
            xt[k] = yt4[base4 + (size_t)k * 8];
        }
        const float* px = (const float*)xp;           // px[k*4 + c]
        const float* pt = (const float*)xt;
        #pragma unroll
        for (int c = 0; c < 4; ++c) {
            const int trk = trkq * 4 + c;
            u16 kk[4];
            #pragma unroll
            for (int r = 0; r < 4; ++r) {
                const float ps = (px[r*4+c] + px[(r+1)*4+c] + px[(r+2)*4+c]
                                + px[(r+3)*4+c] + px[(r+4)*4+c]) * 0.2f;
                const float ts = (pt[r*4+c] + pt[(r+1)*4+c] + pt[(r+2)*4+c]
                                + pt[(r+3)*4+c] + pt[(r+4)*4+c]) * 0.2f;
                uint_t key = 0xFFFFu;
                if (isfinite(ps) && isfinite(ts)) {
                    const int pb = bin_of(ps);
                    const int tb = bin_of(ts);
                    if (pb < 255 && tb < 255) {
                        key = ((uint_t)pb << 8) | (uint_t)tb;
                    } else {
                        const int idx = atomicAdd(&s_ovc, 1);
                        if (idx < OV_CAP)
                            ws[WS_REC_OFF + bid * OV_CAP + idx] = (trk << 20) | (pb << 10) | tb;
                    }
                }
                kk[r] = (u16)key;
            }
            *(ushort4*)&keys[(size_t)trk * KS16 + (size_t)g * 4] =
                make_ushort4(kk[0], kk[1], kk[2], kk[3]);
        }
    }
    __syncthreads();
    if (tid == 0) ws[WS_CNT_OFF + bid] = min(s_ovc, OV_CAP);
}

// ---- K2: {square hist quarters + marginals} || {zero rest of joint} ----
__global__ __launch_bounds__(512) void k2_main(
    const int* __restrict__ ws, int* __restrict__ out)
{
    extern __shared__ int hist[];                 // 64 * HSTRIDE ints (66,560 B)
    const int tid = threadIdx.x;
    const int bid = blockIdx.x;

    int* __restrict__ pred_g  = out;
    int* __restrict__ targ_g  = out + TT * NBINS;
    int* __restrict__ joint_g = out + 2 * TT * NBINS;

    if (bid < NHIST) {
        const int t  = bid & 31;                  // 4 quarters of a track -> same XCD
        const int q  = bid >> 5;
        const int r0 = q * 64;
        int* __restrict__ joint_t = joint_g + (size_t)t * NBINS * NBINS;
        const u16* __restrict__ kt =
            (const u16*)(ws + WS_KEYS_INT_OFF) + (size_t)t * KS16;

        for (int i = tid; i < 64 * HSTRIDE; i += 512) hist[i] = 0;
        __syncthreads();

        int c00 = 0;
        #pragma unroll 4
        for (int p = 0; p < 16; ++p) {
            const int i8 = tid + p * 512;         // uint4 = 8 keys
            if (i8 < NSAMP / 8) {
                const uint4 w = *(const uint4*)&kt[i8 * 8];
                const uint_t dw[4] = {w.x, w.y, w.z, w.w};
                #pragma unroll
                for (int h = 0; h < 4; ++h) {
                    const uint_t lo = dw[h] & 0xFFFFu;
                    const uint_t hi = dw[h] >> 16;
                    if (lo != 0xFFFFu) {
                        const uint_t rr = (lo >> 8) - (uint_t)r0;
                        if (rr < 64u) {
                            if (lo == 0u) c00++;              // only reachable at q==0
                            else atomicAdd(&hist[rr * HSTRIDE + (lo & 255u)], 1);
                        }
                    }
                    if (hi != 0xFFFFu) {
                        const uint_t rr = (hi >> 8) - (uint_t)r0;
                        if (rr < 64u) {
                            if (hi == 0u) c00++;
                            else atomicAdd(&hist[rr * HSTRIDE + (hi & 255u)], 1);
                        }
                    }
                }
            }
        }
        if (c00) atomicAdd(&hist[0], c00);
        __syncthreads();

        // square tile: plain int4 stores (sole writer of this region)
        for (int i = tid; i < 64 * 64; i += 512) {
            const int r  = i >> 6;
            const int c4 = i & 63;
            *(int4*)&joint_t[(size_t)(r0 + r) * NBINS + c4 * 4] =
                *(const int4*)&hist[r * HSTRIDE + c4 * 4];
        }
        // pred marginal rows r0..r0+63: plain store (K3 patches >=255 later)
        {
            const int r = tid >> 3, s = tid & 7;
            int sum = 0;
            #pragma unroll
            for (int k = 0; k < 32; ++k)
                sum += hist[r * HSTRIDE + s * 32 + ((k + tid) & 31)];
            sum += __shfl_xor(sum, 1);
            sum += __shfl_xor(sum, 2);
            sum += __shfl_xor(sum, 4);
            if (s == 0) pred_g[t * NBINS + r0 + r] = sum;
        }
        // targ marginal cols 0..255: partial col sums, atomic into K1-zeroed base
        {
            const int c = tid >> 1, u = tid & 1;
            int sum = 0;
            #pragma unroll
            for (int r = 0; r < 32; ++r)
                sum += hist[(u * 32 + r) * HSTRIDE + c];
            sum += __shfl_xor(sum, 1);
            if (u == 0 && sum) atomicAdd(&targ_g[t * NBINS + c], sum);
        }
    } else {
        int4* __restrict__ j4 = (int4*)joint_g;
        for (int v = ZA1 + (bid - NHIST) * 512 + tid; v < REGION_TOT; v += NZB * 512)
            *zaddr(j4, v) = make_int4(0, 0, 0, 0);
    }
}

// ---- K3: apply rare overflow records (joint + both marginals) ----
__global__ __launch_bounds__(256) void k3_patch(
    const int* __restrict__ ws, int* __restrict__ out)
{
    int* __restrict__ pred_g  = out;
    int* __restrict__ targ_g  = out + TT * NBINS;
    int* __restrict__ joint_g = out + 2 * TT * NBINS;
    const int b = threadIdx.x;
    if (b < K1_BLOCKS) {
        const int cnt = ws[WS_CNT_OFF + b];
        for (int k = 0; k < cnt; ++k) {
            const int rec = ws[WS_REC_OFF + b * OV_CAP + k];
            const int trk = rec >> 20;
            const int pb  = (rec >> 10) & 1023;
            const int tb  = rec & 1023;
            atomicAdd(&joint_g[(size_t)trk * NBINS * NBINS + pb * NBINS + tb], 1);
            atomicAdd(&pred_g[trk * NBINS + pb], 1);
            atomicAdd(&targ_g[trk * NBINS + tb], 1);
        }
    }
}

// ---------------- fallback (proven round-2 path) if ws too small ----------------
__global__ __launch_bounds__(256) void fb_zero(int4* __restrict__ p, int n4) {
    const int i = blockIdx.x * 256 + threadIdx.x;
    if (i < n4) p[i] = make_int4(0, 0, 0, 0);
}

__global__ __launch_bounds__(512) void fb_hist(
    const float* __restrict__ yp, const float* __restrict__ yt,
    int* __restrict__ out)
{
    __shared__ int s_h[16 * 1009];
    const int tid = threadIdx.x;
    const int trk = tid & 15;
    const int slot = tid >> 4;
    const int t = blockIdx.y * 16 + trk;

    for (int i = tid; i < 16 * 1009; i += 512) s_h[i] = 0;
    __syncthreads();
    int* __restrict__ reg = &s_h[trk * 1009];
    int* __restrict__ pred_g  = out;
    int* __restrict__ targ_g  = out + TT * NBINS;
    int* __restrict__ joint_g = out + 2 * TT * NBINS;
    int* __restrict__ joint_t = joint_g + (size_t)t * NBINS * NBINS;
    int c00 = 0, cp0 = 0, ct0 = 0;
    const int g0 = blockIdx.x * 128;
    #pragma unroll
    for (int pass = 0; pass < 4; ++pass) {
        const int g = g0 + pass * 32 + slot;
        if (g < NGROUPS) {
            const int b = g / NGPB;
            const int j = g - b * NGPB;
            const size_t base = ((size_t)b * LL + 4 * (size_t)j) * TT + t;
            float xp[8], xt[8];
            #pragma unroll
            for (int k = 0; k < 8; ++k) {
                xp[k] = yp[base + (size_t)k * TT];
                xt[k] = yt[base + (size_t)k * TT];
            }
            #pragma unroll
            for (int r = 0; r < 4; ++r) {
                const float ps = (xp[r]+xp[r+1]+xp[r+2]+xp[r+3]+xp[r+4]) * 0.2f;
                const float ts = (xt[r]+xt[r+1]+xt[r+2]+xt[r+3]+xt[r+4]) * 0.2f;
                if (!(isfinite(ps) && isfinite(ts))) continue;
                const int pb = bin_of(ps);
                const int tb = bin_of(ts);
                if (pb == 0) cp0++;
                else if (pb < 136) atomicAdd(&reg[736 + pb], 1);
                else atomicAdd(&pred_g[t * NBINS + pb], 1);
                if (tb == 0) ct0++;
                else if (tb < 136) atomicAdd(&reg[872 + tb], 1);
                else atomicAdd(&targ_g[t * NBINS + tb], 1);
                if (pb == 0 && tb == 0) c00++;
                else if (pb < 16 && tb < 16) atomicAdd(&reg[pb * 16 + tb], 1);
                else if (pb == 0 && tb < 256) atomicAdd(&reg[256 + tb - 16], 1);
                else if (tb == 0 && pb < 256) atomicAdd(&reg[496 + pb - 16], 1);
                else atomicAdd(&joint_t[pb * NBINS + tb], 1);
            }
        }
    }
    if (c00) atomicAdd(&reg[0],   c00);
    if (cp0) atomicAdd(&reg[736], cp0);
    if (ct0) atomicAdd(&reg[872], ct0);
    __syncthreads();
    const int h0 = blockIdx.y * 16;
    for (int i = tid; i < 16 * 1008; i += 512) {
        const int tr = i / 1008;
        const int sl = i - tr * 1008;
        const int c  = s_h[tr * 1009 + sl];
        if (c == 0) continue;
        const int tg = h0 + tr;
        if (sl < 256) atomicAdd(&joint_g[(size_t)tg * NBINS * NBINS + (sl >> 4) * NBINS + (sl & 15)], c);
        else if (sl < 496) atomicAdd(&joint_g[(size_t)tg * NBINS * NBINS + (sl - 240)], c);
        else if (sl < 736) atomicAdd(&joint_g[(size_t)tg * NBINS * NBINS + (size_t)(sl - 480) * NBINS], c);
        else if (sl < 872) atomicAdd(&pred_g[tg * NBINS + (sl - 736)], c);
        else atomicAdd(&targ_g[tg * NBINS + (sl - 872)], c);
    }
}

extern "C" void kernel_launch(void* const* d_in, const int* in_sizes, int n_in,
                              void* d_out, int out_size, void* d_ws, size_t ws_size,
                              hipStream_t stream) {
    const float* yp = (const float*)d_in[0];
    const float* yt = (const float*)d_in[1];
    int* out = (int*)d_out;

    if (ws_size >= WS_NEEDED) {
        int* ws = (int*)d_ws;
        k1_bin<<<K1_BLOCKS, 512, 0, stream>>>(yp, yt, out, ws);
        k2_main<<<NHIST + NZB, 512, 64 * HSTRIDE * sizeof(int), stream>>>(ws, out);
        k3_patch<<<1, 256, 0, stream>>>(ws, out);
    } else {
        const int n4 = out_size / 4;
        fb_zero<<<(n4 + 255) / 256, 256, 0, stream>>>((int4*)out, n4);
        dim3 grid((NGROUPS + 127) / 128, 2);
        fb_hist<<<grid, 512, 0, stream>>>(yp, yt, out);
    }
}

// Round 11
// 39.222 us; speedup vs baseline: 1.0300x; 1.0300x over previous
//
#include <hip/hip_runtime.h>

typedef unsigned int uint_t;
typedef unsigned short u16;

#define LL 8192
#define TT 32
#define NGPB 2047                    // 4-sample groups per batch
#define NGROUPS 16376                // 8 * NGPB
#define NSAMP 65504                  // samples per track
#define KS16 65536                   // per-track key stride (ushorts)
#define NBINS 1000
#define K1_BLOCKS 256
#define OV_CAP 8
#define OV_SLOTS (K1_BLOCKS * OV_CAP)
#define HSTRIDE 260                  // LDS row stride (ints)
#define NHIST 128                    // hist blocks (32 tracks x 4 row-quarters)
#define NZB 1920                     // zero blocks
#define REGION_A 5952000             // int4s: rows 256..999, all tracks (contiguous/track)
#define ZA1 1500000                  // int4s zeroed by K1 (24 MB, round-9 optimum)
// ws layout (ints): [0,256) ov counts; [256,2304) ov records; keys @ int 4096
#define WS_CNT_OFF 0
#define WS_REC_OFF 256
#define WS_KEYS_INT_OFF 4096
#define WS_NEEDED ((size_t)WS_KEYS_INT_OFF * 4 + (size_t)TT * KS16 * 2)

__device__ __forceinline__ int bin_of(float v) {
    v = fminf(fmaxf(v, 0.0f), 10.0f);
    int b = (int)ceilf(v * 100.0f) - 1;
    b = b < 0 ? 0 : b;
    return b > (NBINS - 1) ? (NBINS - 1) : b;
}

// REGION_A linear index -> int4 address (rows 256..999 contiguous per track)
__device__ __forceinline__ int4* zaddr(int4* __restrict__ j4, int v) {
    const int trk = v / 186000;
    const int rem = v - trk * 186000;
    return j4 + (size_t)trk * 250000 + 64000 + rem;
}

// ---- K1: zero 24MB share + marginals; bin (float4 track-quads) -> u16 keys ----
__global__ __launch_bounds__(512) void k1_bin(
    const float* __restrict__ yp, const float* __restrict__ yt,
    int* __restrict__ out, int* __restrict__ ws)
{
    __shared__ int s_ovc;
    const int tid = threadIdx.x;
    const int bid = blockIdx.x;
    if (tid == 0) s_ovc = 0;
    if (tid < 250) out[bid * 250 + tid] = 0;          // 256*250 = 64,000 marginal ints
    __syncthreads();

    // zero share first: stores drain under the bin compute below
    int4* __restrict__ j4 = (int4*)(out + 2 * TT * NBINS);
    for (int v = bid * 512 + tid; v < ZA1; v += K1_BLOCKS * 512)
        *zaddr(j4, v) = make_int4(0, 0, 0, 0);

    u16* __restrict__ keys = (u16*)(ws + WS_KEYS_INT_OFF);
    const int trkq  = tid & 7;                        // track quad (4 tracks)
    const int slotg = tid >> 3;                       // 0..63
    const int g = bid * 64 + slotg;

    if (g < NGROUPS) {
        const int b = g / NGPB;
        const int j = g - b * NGPB;
        const float4* __restrict__ yp4 = (const float4*)yp;
        const float4* __restrict__ yt4 = (const float4*)yt;
        const size_t base4 = ((size_t)b * LL + 4 * (size_t)j) * 8 + trkq;  // float4 units
        float4 xp[8], xt[8];
        #pragma unroll
        for (int k = 0; k < 8; ++k) {
            xp[k] = yp4[base4 + (size_t)k * 8];
            xt[k] = yt4[base4 + (size_t)k * 8];
        }
        const float* px = (const float*)xp;           // px[k*4 + c]
        const float* pt = (const float*)xt;
        #pragma unroll
        for (int c = 0; c < 4; ++c) {
            const int trk = trkq * 4 + c;
            u16 kk[4];
            #pragma unroll
            for (int r = 0; r < 4; ++r) {
                const float ps = (px[r*4+c] + px[(r+1)*4+c] + px[(r+2)*4+c]
                                + px[(r+3)*4+c] + px[(r+4)*4+c]) * 0.2f;
                const float ts = (pt[r*4+c] + pt[(r+1)*4+c] + pt[(r+2)*4+c]
                                + pt[(r+3)*4+c] + pt[(r+4)*4+c]) * 0.2f;
                uint_t key = 0xFFFFu;
                if (isfinite(ps) && isfinite(ts)) {
                    const int pb = bin_of(ps);
                    const int tb = bin_of(ts);
                    if (pb < 255 && tb < 255) {
                        key = ((uint_t)pb << 8) | (uint_t)tb;
                    } else {
                        const int idx = atomicAdd(&s_ovc, 1);
                        if (idx < OV_CAP)
                            ws[WS_REC_OFF + bid * OV_CAP + idx] = (trk << 20) | (pb << 10) | tb;
                    }
                }
                kk[r] = (u16)key;
            }
            *(ushort4*)&keys[(size_t)trk * KS16 + (size_t)g * 4] =
                make_ushort4(kk[0], kk[1], kk[2], kk[3]);
        }
    }
    __syncthreads();
    if (tid == 0) ws[WS_CNT_OFF + bid] = min(s_ovc, OV_CAP);
}

// ---- K2: {hist quarters, full-row stores} || {zero rows 256..999}; inline patch ----
__global__ __launch_bounds__(512) void k2_main(
    const int* __restrict__ ws, int* __restrict__ out)
{
    extern __shared__ int hist[];                 // 64 * HSTRIDE ints (66,560 B)
    __shared__ int s_any;
    const int tid = threadIdx.x;
    const int bid = blockIdx.x;

    int* __restrict__ pred_g  = out;
    int* __restrict__ targ_g  = out + TT * NBINS;
    int* __restrict__ joint_g = out + 2 * TT * NBINS;

    if (tid == 0) s_any = 0;

    if (bid < NHIST) {
        const int t  = bid & 31;                  // 4 quarters of a track -> same XCD
        const int q  = bid >> 5;
        const int r0 = q * 64;
        int* __restrict__ joint_t = joint_g + (size_t)t * NBINS * NBINS;
        const u16* __restrict__ kt =
            (const u16*)(ws + WS_KEYS_INT_OFF) + (size_t)t * KS16;

        for (int i = tid; i < 64 * HSTRIDE; i += 512) hist[i] = 0;
        __syncthreads();
        if (tid < K1_BLOCKS && ws[WS_CNT_OFF + tid] != 0) s_any = 1;

        int c00 = 0;
        #pragma unroll 4
        for (int p = 0; p < 16; ++p) {
            const int i8 = tid + p * 512;         // uint4 = 8 keys
            if (i8 < NSAMP / 8) {
                const uint4 w = *(const uint4*)&kt[i8 * 8];
                const uint_t dw[4] = {w.x, w.y, w.z, w.w};
                #pragma unroll
                for (int h = 0; h < 4; ++h) {
                    const uint_t lo = dw[h] & 0xFFFFu;
                    const uint_t hi = dw[h] >> 16;
                    if (lo != 0xFFFFu) {
                        const uint_t rr = (lo >> 8) - (uint_t)r0;
                        if (rr < 64u) {
                            if (lo == 0u) c00++;              // only reachable at q==0
                            else atomicAdd(&hist[rr * HSTRIDE + (lo & 255u)], 1);
                        }
                    }
                    if (hi != 0xFFFFu) {
                        const uint_t rr = (hi >> 8) - (uint_t)r0;
                        if (rr < 64u) {
                            if (hi == 0u) c00++;
                            else atomicAdd(&hist[rr * HSTRIDE + (hi & 255u)], 1);
                        }
                    }
                }
            }
        }
        if (c00) atomicAdd(&hist[0], c00);
        __syncthreads();

        // full rows r0..r0+63, cols 0..999: cols<256 from LDS, rest zero (sequential 4KB rows)
        int4* __restrict__ jt4 = (int4*)joint_t;
        for (int i = tid; i < 64 * 250; i += 512) {
            const int r  = i / 250;
            const int c4 = i - r * 250;
            int4 val;
            if (c4 < 64) val = *(const int4*)&hist[r * HSTRIDE + c4 * 4];
            else         val = make_int4(0, 0, 0, 0);
            jt4[(size_t)(r0 + r) * 250 + c4] = val;
        }
        // pred marginal rows r0..r0+63: plain store
        {
            const int r = tid >> 3, s = tid & 7;
            int sum = 0;
            #pragma unroll
            for (int k = 0; k < 32; ++k)
                sum += hist[r * HSTRIDE + s * 32 + ((k + tid) & 31)];
            sum += __shfl_xor(sum, 1);
            sum += __shfl_xor(sum, 2);
            sum += __shfl_xor(sum, 4);
            if (s == 0) pred_g[t * NBINS + r0 + r] = sum;
        }
        // targ marginal cols 0..255: partial col sums, atomic into K1-zeroed base
        {
            const int c = tid >> 1, u = tid & 1;
            int sum = 0;
            #pragma unroll
            for (int r = 0; r < 32; ++r)
                sum += hist[(u * 32 + r) * HSTRIDE + c];
            sum += __shfl_xor(sum, 1);
            if (u == 0 && sum) atomicAdd(&targ_g[t * NBINS + c], sum);
        }
        __syncthreads();                           // stores drained before patches

        if (s_any) {                               // rare-path overflow patches
            for (int idx = tid; idx < OV_SLOTS; idx += 512) {
                const int b2 = idx >> 3, k = idx & 7;
                if (k >= ws[WS_CNT_OFF + b2]) continue;
                const int rec = ws[WS_REC_OFF + b2 * OV_CAP + k];
                const int trk = rec >> 20;
                const int pb  = (rec >> 10) & 1023;
                const int tb  = rec & 1023;
                if (trk == t && pb < 256 && (pb >> 6) == q) {   // our rows
                    atomicAdd(&joint_t[(size_t)pb * NBINS + tb], 1);
                    atomicAdd(&pred_g[t * NBINS + pb], 1);
                }
                if (trk == t && q == 0)                          // targ owner
                    atomicAdd(&targ_g[t * NBINS + tb], 1);
                if (bid == 0) {
                    if (pb >= 256)                               // pred high rows
                        atomicAdd(&pred_g[trk * NBINS + pb], 1);
                    if (pb >= 256) {                             // joint in K1's zero share
                        const int v = trk * 186000 + (pb - 256) * 250 + (tb >> 2);
                        if (v < ZA1)
                            atomicAdd(&joint_g[(size_t)trk * NBINS * NBINS
                                               + (size_t)pb * NBINS + tb], 1);
                    }
                }
            }
        }
    } else {
        // zero role: REGION_A remainder, contiguous per track
        int4* __restrict__ j4 = (int4*)joint_g;
        for (int v = ZA1 + (bid - NHIST) * 512 + tid; v < REGION_A; v += NZB * 512)
            *zaddr(j4, v) = make_int4(0, 0, 0, 0);
        __syncthreads();
        if (tid < K1_BLOCKS && ws[WS_CNT_OFF + tid] != 0) s_any = 1;
        __syncthreads();

        if (s_any) {
            for (int idx = tid; idx < OV_SLOTS; idx += 512) {
                const int b2 = idx >> 3, k = idx & 7;
                if (k >= ws[WS_CNT_OFF + b2]) continue;
                const int rec = ws[WS_REC_OFF + b2 * OV_CAP + k];
                const int trk = rec >> 20;
                const int pb  = (rec >> 10) & 1023;
                const int tb  = rec & 1023;
                if (pb >= 256) {
                    const int v = trk * 186000 + (pb - 256) * 250 + (tb >> 2);
                    if (v >= ZA1 && (NHIST + (((v - ZA1) >> 9) % NZB)) == bid)
                        atomicAdd(&joint_g[(size_t)trk * NBINS * NBINS
                                           + (size_t)pb * NBINS + tb], 1);
                }
            }
        }
    }
}

// ---------------- fallback (proven round-2 path) if ws too small ----------------
__global__ __launch_bounds__(256) void fb_zero(int4* __restrict__ p, int n4) {
    const int i = blockIdx.x * 256 + threadIdx.x;
    if (i < n4) p[i] = make_int4(0, 0, 0, 0);
}

__global__ __launch_bounds__(512) void fb_hist(
    const float* __restrict__ yp, const float* __restrict__ yt,
    int* __restrict__ out)
{
    __shared__ int s_h[16 * 1009];
    const int tid = threadIdx.x;
    const int trk = tid & 15;
    const int slot = tid >> 4;
    const int t = blockIdx.y * 16 + trk;

    for (int i = tid; i < 16 * 1009; i += 512) s_h[i] = 0;
    __syncthreads();
    int* __restrict__ reg = &s_h[trk * 1009];
    int* __restrict__ pred_g  = out;
    int* __restrict__ targ_g  = out + TT * NBINS;
    int* __restrict__ joint_g = out + 2 * TT * NBINS;
    int* __restrict__ joint_t = joint_g + (size_t)t * NBINS * NBINS;
    int c00 = 0, cp0 = 0, ct0 = 0;
    const int g0 = blockIdx.x * 128;
    #pragma unroll
    for (int pass = 0; pass < 4; ++pass) {
        const int g = g0 + pass * 32 + slot;
        if (g < NGROUPS) {
            const int b = g / NGPB;
            const int j = g - b * NGPB;
            const size_t base = ((size_t)b * LL + 4 * (size_t)j) * TT + t;
            float xp[8], xt[8];
            #pragma unroll
            for (int k = 0; k < 8; ++k) {
                xp[k] = yp[base + (size_t)k * TT];
                xt[k] = yt[base + (size_t)k * TT];
            }
            #pragma unroll
            for (int r = 0; r < 4; ++r) {
                const float ps = (xp[r]+xp[r+1]+xp[r+2]+xp[r+3]+xp[r+4]) * 0.2f;
                const float ts = (xt[r]+xt[r+1]+xt[r+2]+xt[r+3]+xt[r+4]) * 0.2f;
                if (!(isfinite(ps) && isfinite(ts))) continue;
                const int pb = bin_of(ps);
                const int tb = bin_of(ts);
                if (pb == 0) cp0++;
                else if (pb < 136) atomicAdd(&reg[736 + pb], 1);
                else atomicAdd(&pred_g[t * NBINS + pb], 1);
                if (tb == 0) ct0++;
                else if (tb < 136) atomicAdd(&reg[872 + tb], 1);
                else atomicAdd(&targ_g[t * NBINS + tb], 1);
                if (pb == 0 && tb == 0) c00++;
                else if (pb < 16 && tb < 16) atomicAdd(&reg[pb * 16 + tb], 1);
                else if (pb == 0 && tb < 256) atomicAdd(&reg[256 + tb - 16], 1);
                else if (tb == 0 && pb < 256) atomicAdd(&reg[496 + pb - 16], 1);
                else atomicAdd(&joint_t[pb * NBINS + tb], 1);
            }
        }
    }
    if (c00) atomicAdd(&reg[0],   c00);
    if (cp0) atomicAdd(&reg[736], cp0);
    if (ct0) atomicAdd(&reg[872], ct0);
    __syncthreads();
    const int h0 = blockIdx.y * 16;
    for (int i = tid; i < 16 * 1008; i += 512) {
        const int tr = i / 1008;
        const int sl = i - tr * 1008;
        const int c  = s_h[tr * 1009 + sl];
        if (c == 0) continue;
        const int tg = h0 + tr;
        if (sl < 256) atomicAdd(&joint_g[(size_t)tg * NBINS * NBINS + (sl >> 4) * NBINS + (sl & 15)], c);
        else if (sl < 496) atomicAdd(&joint_g[(size_t)tg * NBINS * NBINS + (sl - 240)], c);
        else if (sl < 736) atomicAdd(&joint_g[(size_t)tg * NBINS * NBINS + (size_t)(sl - 480) * NBINS], c);
        else if (sl < 872) atomicAdd(&pred_g[tg * NBINS + (sl - 736)], c);
        else atomicAdd(&targ_g[tg * NBINS + (sl - 872)], c);
    }
}

extern "C" void kernel_launch(void* const* d_in, const int* in_sizes, int n_in,
                              void* d_out, int out_size, void* d_ws, size_t ws_size,
                              hipStream_t stream) {
    const float* yp = (const float*)d_in[0];
    const float* yt = (const float*)d_in[1];
    int* out = (int*)d_out;

    if (ws_size >= WS_NEEDED) {
        int* ws = (int*)d_ws;
        k1_bin<<<K1_BLOCKS, 512, 0, stream>>>(yp, yt, out, ws);
        k2_main<<<NHIST + NZB, 512, 64 * HSTRIDE * sizeof(int), stream>>>(ws, out);
    } else {
        const int n4 = out_size / 4;
        fb_zero<<<(n4 + 255) / 256, 256, 0, stream>>>((int4*)out, n4);
        dim3 grid((NGROUPS + 127) / 128, 2);
        fb_hist<<<grid, 512, 0, stream>>>(yp, yt, out);
    }
}

// Round 12
// 39.024 us; speedup vs baseline: 1.0352x; 1.0051x over previous
//
#include <hip/hip_runtime.h>

typedef unsigned int uint_t;
typedef unsigned short u16;

#define LL 8192
#define TT 32
#define NGPB 2047                    // 4-sample groups per batch
#define NGROUPS 16376                // 8 * NGPB
#define NSAMP 65504                  // samples per track
#define KS16 65536                   // per-track key stride (ushorts)
#define NBINS 1000
#define K1_BLOCKS 256                // bin-role blocks in K1
#define K1_GRID 1024                 // + 768 zero-role blocks
#define K1_NZ (K1_GRID - K1_BLOCKS)
#define OV_CAP 8
#define OV_SLOTS (K1_BLOCKS * OV_CAP)
#define HSTRIDE 260                  // LDS row stride (ints)
#define NHIST 128                    // hist blocks (32 tracks x 4 row-quarters)
#define NZB 1920                     // zero blocks in K2
#define REGION_A 5952000             // int4s: rows 256..999, all tracks (contig per track)
#define ZA2 3538944                  // int4s zeroed by K1 zero-role (9 iters x 768 x 512)
// ws layout (ints): [0,256) ov counts; [256,2304) ov records; keys @ int 4096
#define WS_CNT_OFF 0
#define WS_REC_OFF 256
#define WS_KEYS_INT_OFF 4096
#define WS_NEEDED ((size_t)WS_KEYS_INT_OFF * 4 + (size_t)TT * KS16 * 2)

__device__ __forceinline__ int bin_of(float v) {
    v = fminf(fmaxf(v, 0.0f), 10.0f);
    int b = (int)ceilf(v * 100.0f) - 1;
    b = b < 0 ? 0 : b;
    return b > (NBINS - 1) ? (NBINS - 1) : b;
}

// REGION_A linear index -> int4 address (rows 256..999 contiguous per track)
__device__ __forceinline__ int4* zaddr(int4* __restrict__ j4, int v) {
    const int trk = v / 186000;
    const int rem = v - trk * 186000;
    return j4 + (size_t)trk * 250000 + 64000 + rem;
}

// ---- K1: {bin (loads first, no store hazard)} || {zero 56.6MB of REGION_A} ----
__global__ __launch_bounds__(512) void k1_bin(
    const float* __restrict__ yp, const float* __restrict__ yt,
    int* __restrict__ out, int* __restrict__ ws)
{
    __shared__ int s_ovc;
    const int tid = threadIdx.x;
    const int bid = blockIdx.x;

    if (bid >= K1_BLOCKS) {                           // zero role: pure fill stream
        int4* __restrict__ j4 = (int4*)(out + 2 * TT * NBINS);
        for (int v = (bid - K1_BLOCKS) * 512 + tid; v < ZA2; v += K1_NZ * 512)
            *zaddr(j4, v) = make_int4(0, 0, 0, 0);
        return;
    }

    if (tid == 0) s_ovc = 0;
    if (tid < 250) out[bid * 250 + tid] = 0;          // 256*250 = 64,000 marginal ints
    __syncthreads();

    u16* __restrict__ keys = (u16*)(ws + WS_KEYS_INT_OFF);
    const int trkq  = tid & 7;                        // track quad (4 tracks)
    const int slotg = tid >> 3;                       // 0..63
    const int g = bid * 64 + slotg;

    if (g < NGROUPS) {
        const int b = g / NGPB;
        const int j = g - b * NGPB;
        const float4* __restrict__ yp4 = (const float4*)yp;
        const float4* __restrict__ yt4 = (const float4*)yt;
        const size_t base4 = ((size_t)b * LL + 4 * (size_t)j) * 8 + trkq;  // float4 units
        float4 xp[8], xt[8];
        #pragma unroll
        for (int k = 0; k < 8; ++k) {                 // loads first, nothing ahead in vmcnt
            xp[k] = yp4[base4 + (size_t)k * 8];
            xt[k] = yt4[base4 + (size_t)k * 8];
        }
        const float* px = (const float*)xp;           // px[k*4 + c]
        const float* pt = (const float*)xt;
        #pragma unroll
        for (int c = 0; c < 4; ++c) {
            const int trk = trkq * 4 + c;
            u16 kk[4];
            #pragma unroll
            for (int r = 0; r < 4; ++r) {
                const float ps = (px[r*4+c] + px[(r+1)*4+c] + px[(r+2)*4+c]
                                + px[(r+3)*4+c] + px[(r+4)*4+c]) * 0.2f;
                const float ts = (pt[r*4+c] + pt[(r+1)*4+c] + pt[(r+2)*4+c]
                                + pt[(r+3)*4+c] + pt[(r+4)*4+c]) * 0.2f;
                uint_t key = 0xFFFFu;
                if (isfinite(ps) && isfinite(ts)) {
                    const int pb = bin_of(ps);
                    const int tb = bin_of(ts);
                    if (pb < 255 && tb < 255) {
                        key = ((uint_t)pb << 8) | (uint_t)tb;
                    } else {
                        const int idx = atomicAdd(&s_ovc, 1);
                        if (idx < OV_CAP)
                            ws[WS_REC_OFF + bid * OV_CAP + idx] = (trk << 20) | (pb << 10) | tb;
                    }
                }
                kk[r] = (u16)key;
            }
            *(ushort4*)&keys[(size_t)trk * KS16 + (size_t)g * 4] =
                make_ushort4(kk[0], kk[1], kk[2], kk[3]);
        }
    }
    __syncthreads();
    if (tid == 0) ws[WS_CNT_OFF + bid] = min(s_ovc, OV_CAP);
}

// ---- K2: {hist quarters, full-row stores} || {zero REGION_A remainder}; inline patch ----
__global__ __launch_bounds__(512) void k2_main(
    const int* __restrict__ ws, int* __restrict__ out)
{
    extern __shared__ int hist[];                 // 64 * HSTRIDE ints (66,560 B)
    __shared__ int s_any;
    const int tid = threadIdx.x;
    const int bid = blockIdx.x;

    int* __restrict__ pred_g  = out;
    int* __restrict__ targ_g  = out + TT * NBINS;
    int* __restrict__ joint_g = out + 2 * TT * NBINS;

    if (tid == 0) s_any = 0;

    if (bid < NHIST) {
        const int t  = bid & 31;                  // 4 quarters of a track -> same XCD
        const int q  = bid >> 5;
        const int r0 = q * 64;
        int* __restrict__ joint_t = joint_g + (size_t)t * NBINS * NBINS;
        const u16* __restrict__ kt =
            (const u16*)(ws + WS_KEYS_INT_OFF) + (size_t)t * KS16;

        for (int i = tid; i < 64 * HSTRIDE; i += 512) hist[i] = 0;
        __syncthreads();
        if (tid < K1_BLOCKS && ws[WS_CNT_OFF + tid] != 0) s_any = 1;

        int c00 = 0;
        #pragma unroll 4
        for (int p = 0; p < 16; ++p) {
            const int i8 = tid + p * 512;         // uint4 = 8 keys
            if (i8 < NSAMP / 8) {
                const uint4 w = *(const uint4*)&kt[i8 * 8];
                const uint_t dw[4] = {w.x, w.y, w.z, w.w};
                #pragma unroll
                for (int h = 0; h < 4; ++h) {
                    const uint_t lo = dw[h] & 0xFFFFu;
                    const uint_t hi = dw[h] >> 16;
                    if (lo != 0xFFFFu) {
                        const uint_t rr = (lo >> 8) - (uint_t)r0;
                        if (rr < 64u) {
                            if (lo == 0u) c00++;              // only reachable at q==0
                            else atomicAdd(&hist[rr * HSTRIDE + (lo & 255u)], 1);
                        }
                    }
                    if (hi != 0xFFFFu) {
                        const uint_t rr = (hi >> 8) - (uint_t)r0;
                        if (rr < 64u) {
                            if (hi == 0u) c00++;
                            else atomicAdd(&hist[rr * HSTRIDE + (hi & 255u)], 1);
                        }
                    }
                }
            }
        }
        if (c00) atomicAdd(&hist[0], c00);
        __syncthreads();

        // full rows r0..r0+63, cols 0..999: cols<256 from LDS, rest zero (4KB seq rows)
        int4* __restrict__ jt4 = (int4*)joint_t;
        for (int i = tid; i < 64 * 250; i += 512) {
            const int r  = i / 250;
            const int c4 = i - r * 250;
            int4 val;
            if (c4 < 64) val = *(const int4*)&hist[r * HSTRIDE + c4 * 4];
            else         val = make_int4(0, 0, 0, 0);
            jt4[(size_t)(r0 + r) * 250 + c4] = val;
        }
        // pred marginal rows r0..r0+63: plain store
        {
            const int r = tid >> 3, s = tid & 7;
            int sum = 0;
            #pragma unroll
            for (int k = 0; k < 32; ++k)
                sum += hist[r * HSTRIDE + s * 32 + ((k + tid) & 31)];
            sum += __shfl_xor(sum, 1);
            sum += __shfl_xor(sum, 2);
            sum += __shfl_xor(sum, 4);
            if (s == 0) pred_g[t * NBINS + r0 + r] = sum;
        }
        // targ marginal cols 0..255: partial col sums, atomic into K1-zeroed base
        {
            const int c = tid >> 1, u = tid & 1;
            int sum = 0;
            #pragma unroll
            for (int r = 0; r < 32; ++r)
                sum += hist[(u * 32 + r) * HSTRIDE + c];
            sum += __shfl_xor(sum, 1);
            if (u == 0 && sum) atomicAdd(&targ_g[t * NBINS + c], sum);
        }
        __syncthreads();                           // drains stores before patches

        if (s_any) {                               // rare-path overflow patches
            for (int idx = tid; idx < OV_SLOTS; idx += 512) {
                const int b2 = idx >> 3, k = idx & 7;
                if (k >= ws[WS_CNT_OFF + b2]) continue;
                const int rec = ws[WS_REC_OFF + b2 * OV_CAP + k];
                const int trk = rec >> 20;
                const int pb  = (rec >> 10) & 1023;
                const int tb  = rec & 1023;
                if (trk == t && pb < 256 && (pb >> 6) == q) {   // our rows
                    atomicAdd(&joint_t[(size_t)pb * NBINS + tb], 1);
                    atomicAdd(&pred_g[t * NBINS + pb], 1);
                }
                if (trk == t && q == 0)                          // targ owner
                    atomicAdd(&targ_g[t * NBINS + tb], 1);
                if (bid == 0) {
                    if (pb >= 256) {
                        atomicAdd(&pred_g[trk * NBINS + pb], 1); // pred high rows
                        const int v = trk * 186000 + (pb - 256) * 250 + (tb >> 2);
                        if (v < ZA2)                             // joint in K1's zeroed share
                            atomicAdd(&joint_g[(size_t)trk * NBINS * NBINS
                                               + (size_t)pb * NBINS + tb], 1);
                    }
                }
            }
        }
    } else {
        // zero role: REGION_A remainder, contiguous per track
        int4* __restrict__ j4 = (int4*)joint_g;
        for (int v = ZA2 + (bid - NHIST) * 512 + tid; v < REGION_A; v += NZB * 512)
            *zaddr(j4, v) = make_int4(0, 0, 0, 0);
        __syncthreads();
        if (tid < K1_BLOCKS && ws[WS_CNT_OFF + tid] != 0) s_any = 1;
        __syncthreads();

        if (s_any) {
            for (int idx = tid; idx < OV_SLOTS; idx += 512) {
                const int b2 = idx >> 3, k = idx & 7;
                if (k >= ws[WS_CNT_OFF + b2]) continue;
                const int rec = ws[WS_REC_OFF + b2 * OV_CAP + k];
                const int trk = rec >> 20;
                const int pb  = (rec >> 10) & 1023;
                const int tb  = rec & 1023;
                if (pb >= 256) {
                    const int v = trk * 186000 + (pb - 256) * 250 + (tb >> 2);
                    if (v >= ZA2 && (NHIST + (((v - ZA2) >> 9) % NZB)) == bid)
                        atomicAdd(&joint_g[(size_t)trk * NBINS * NBINS
                                           + (size_t)pb * NBINS + tb], 1);
                }
            }
        }
    }
}

// ---------------- fallback (proven round-2 path) if ws too small ----------------
__global__ __launch_bounds__(256) void fb_zero(int4* __restrict__ p, int n4) {
    const int i = blockIdx.x * 256 + threadIdx.x;
    if (i < n4) p[i] = make_int4(0, 0, 0, 0);
}

__global__ __launch_bounds__(512) void fb_hist(
    const float* __restrict__ yp, const float* __restrict__ yt,
    int* __restrict__ out)
{
    __shared__ int s_h[16 * 1009];
    const int tid = threadIdx.x;
    const int trk = tid & 15;
    const int slot = tid >> 4;
    const int t = blockIdx.y * 16 + trk;

    for (int i = tid; i < 16 * 1009; i += 512) s_h[i] = 0;
    __syncthreads();
    int* __restrict__ reg = &s_h[trk * 1009];
    int* __restrict__ pred_g  = out;
    int* __restrict__ targ_g  = out + TT * NBINS;
    int* __restrict__ joint_g = out + 2 * TT * NBINS;
    int* __restrict__ joint_t = joint_g + (size_t)t * NBINS * NBINS;
    int c00 = 0, cp0 = 0, ct0 = 0;
    const int g0 = blockIdx.x * 128;
    #pragma unroll
    for (int pass = 0; pass < 4; ++pass) {
        const int g = g0 + pass * 32 + slot;
        if (g < NGROUPS) {
            const int b = g / NGPB;
            const int j = g - b * NGPB;
            const size_t base = ((size_t)b * LL + 4 * (size_t)j) * TT + t;
            float xp[8], xt[8];
            #pragma unroll
            for (int k = 0; k < 8; ++k) {
                xp[k] = yp[base + (size_t)k * TT];
                xt[k] = yt[base + (size_t)k * TT];
            }
            #pragma unroll
            for (int r = 0; r < 4; ++r) {
                const float ps = (xp[r]+xp[r+1]+xp[r+2]+xp[r+3]+xp[r+4]) * 0.2f;
                const float ts = (xt[r]+xt[r+1]+xt[r+2]+xt[r+3]+xt[r+4]) * 0.2f;
                if (!(isfinite(ps) && isfinite(ts))) continue;
                const int pb = bin_of(ps);
                const int tb = bin_of(ts);
                if (pb == 0) cp0++;
                else if (pb < 136) atomicAdd(&reg[736 + pb], 1);
                else atomicAdd(&pred_g[t * NBINS + pb], 1);
                if (tb == 0) ct0++;
                else if (tb < 136) atomicAdd(&reg[872 + tb], 1);
                else atomicAdd(&targ_g[t * NBINS + tb], 1);
                if (pb == 0 && tb == 0) c00++;
                else if (pb < 16 && tb < 16) atomicAdd(&reg[pb * 16 + tb], 1);
                else if (pb == 0 && tb < 256) atomicAdd(&reg[256 + tb - 16], 1);
                else if (tb == 0 && pb < 256) atomicAdd(&reg[496 + pb - 16], 1);
                else atomicAdd(&joint_t[pb * NBINS + tb], 1);
            }
        }
    }
    if (c00) atomicAdd(&reg[0],   c00);
    if (cp0) atomicAdd(&reg[736], cp0);
    if (ct0) atomicAdd(&reg[872], ct0);
    __syncthreads();
    const int h0 = blockIdx.y * 16;
    for (int i = tid; i < 16 * 1008; i += 512) {
        const int tr = i / 1008;
        const int sl = i - tr * 1008;
        const int c  = s_h[tr * 1009 + sl];
        if (c == 0) continue;
        const int tg = h0 + tr;
        if (sl < 256) atomicAdd(&joint_g[(size_t)tg * NBINS * NBINS + (sl >> 4) * NBINS + (sl & 15)], c);
        else if (sl < 496) atomicAdd(&joint_g[(size_t)tg * NBINS * NBINS + (sl - 240)], c);
        else if (sl < 736) atomicAdd(&joint_g[(size_t)tg * NBINS * NBINS + (size_t)(sl - 480) * NBINS], c);
        else if (sl < 872) atomicAdd(&pred_g[tg * NBINS + (sl - 736)], c);
        else atomicAdd(&targ_g[tg * NBINS + (sl - 872)], c);
    }
}

extern "C" void kernel_launch(void* const* d_in, const int* in_sizes, int n_in,
                              void* d_out, int out_size, void* d_ws, size_t ws_size,
                              hipStream_t stream) {
    const float* yp = (const float*)d_in[0];
    const float* yt = (const float*)d_in[1];
    int* out = (int*)d_out;

    if (ws_size >= WS_NEEDED) {
        int* ws = (int*)d_ws;
        k1_bin<<<K1_GRID, 512, 0, stream>>>(yp, yt, out, ws);
        k2_main<<<NHIST + NZB, 512, 64 * HSTRIDE * sizeof(int), stream>>>(ws, out);
    } else {
        const int n4 = out_size / 4;
        fb_zero<<<(n4 + 255) / 256, 256, 0, stream>>>((int4*)out, n4);
        dim3 grid((NGROUPS + 127) / 128, 2);
        fb_hist<<<grid, 512, 0, stream>>>(yp, yt, out);
    }
}